// Round 9
// baseline (991.333 us; speedup 1.0000x reference)
//
#include <hip/hip_runtime.h>
#include <math.h>

#define NN 100000
#define NE 800000
#define NG 512
#define NENT (2*NE)
#define NB ((NN + 1023)/1024)

// ---------------------------------------------------------------- prep:
// fold edge encoder through msg layer-1 edge rows:
//   Wef[j][c] = sum_t enc_ew[j][t] * mw1[64+t][c]        (8x32)
//   bef[c]    = mb1[c] + sum_t enc_eb[t] * mw1[64+t][c]  (32)
__global__ __launch_bounds__(64) void k_prep(
    const float* __restrict__ ew, const float* __restrict__ eb,
    const float* __restrict__ mw1, const float* __restrict__ mb1,
    float* __restrict__ Wef, float* __restrict__ bef)
{
    int c = threadIdx.x;
    if (c >= 32) return;
    float bacc = mb1[c];
    for (int t = 0; t < 16; ++t) bacc = fmaf(eb[t], mw1[(64 + t) * 32 + c], bacc);
    bef[c] = bacc;
    for (int j = 0; j < 8; ++j) {
        float acc = 0.f;
        for (int t = 0; t < 16; ++t) acc = fmaf(ew[j * 16 + t], mw1[(64 + t) * 32 + c], acc);
        Wef[j * 32 + c] = acc;
    }
}

// ---------------------------------------------------------------- encoder:
// h = nf @ wn + bn ; A = h @ mw1[0:32] ; B = h @ mw1[32:64]
__global__ __launch_bounds__(256) void k_enc_nodes(
    const float* __restrict__ nf, const float* __restrict__ w,
    const float* __restrict__ bb, const float* __restrict__ mw1,
    float* __restrict__ h, float* __restrict__ A, float* __restrict__ B)
{
    int n = blockIdx.x * 256 + threadIdx.x;
    if (n >= NN) return;
    const float4* px = (const float4*)(nf + (size_t)n * 16);
    float4 x[4];
#pragma unroll
    for (int i = 0; i < 4; ++i) x[i] = px[i];
    float out[32];
#pragma unroll
    for (int j = 0; j < 32; ++j) out[j] = bb[j];
#pragma unroll
    for (int i = 0; i < 4; ++i) {
#pragma unroll
        for (int j = 0; j < 32; ++j) {
            out[j] = fmaf(x[i].x, w[(4*i+0)*32 + j], out[j]);
            out[j] = fmaf(x[i].y, w[(4*i+1)*32 + j], out[j]);
            out[j] = fmaf(x[i].z, w[(4*i+2)*32 + j], out[j]);
            out[j] = fmaf(x[i].w, w[(4*i+3)*32 + j], out[j]);
        }
    }
    float4* po = (float4*)(h + (size_t)n * 32);
#pragma unroll
    for (int j = 0; j < 8; ++j)
        po[j] = make_float4(out[4*j], out[4*j+1], out[4*j+2], out[4*j+3]);

    float Av[32], Bv[32];
#pragma unroll
    for (int c = 0; c < 32; ++c) { Av[c] = 0.f; Bv[c] = 0.f; }
#pragma unroll
    for (int i = 0; i < 32; ++i) {
        float r = out[i];
        const float* wra = mw1 + (size_t)i * 32;
        const float* wrb = mw1 + (size_t)(32 + i) * 32;
#pragma unroll
        for (int c = 0; c < 32; ++c) {
            Av[c] = fmaf(r, wra[c], Av[c]);
            Bv[c] = fmaf(r, wrb[c], Bv[c]);
        }
    }
    float4* pA = (float4*)(A + (size_t)n * 32);
    float4* pB = (float4*)(B + (size_t)n * 32);
#pragma unroll
    for (int j = 0; j < 8; ++j) {
        pA[j] = make_float4(Av[4*j], Av[4*j+1], Av[4*j+2], Av[4*j+3]);
        pB[j] = make_float4(Bv[4*j], Bv[4*j+1], Bv[4*j+2], Bv[4*j+3]);
    }
}

// ---------------------------------------------------------------- CSR build
__global__ __launch_bounds__(256) void k_count(
    const int* __restrict__ fi, const int* __restrict__ ti, int* __restrict__ deg)
{
    int e = blockIdx.x * 256 + threadIdx.x;
    if (e >= NE) return;
    atomicAdd(&deg[ti[e]], 1);
    atomicAdd(&deg[fi[e]], 1);
}

__global__ __launch_bounds__(256) void k_scan1(
    const int* __restrict__ deg, int* __restrict__ offs, int* __restrict__ bsum)
{
    __shared__ int s[256];
    int b = blockIdx.x, t = threadIdx.x;
    int base = b * 1024 + t * 4;
    int v[4];
#pragma unroll
    for (int i = 0; i < 4; ++i) { int g = base + i; v[i] = (g < NN) ? deg[g] : 0; }
    int tsum = v[0] + v[1] + v[2] + v[3];
    s[t] = tsum;
    __syncthreads();
    for (int d = 1; d < 256; d <<= 1) {
        int xv = (t >= d) ? s[t - d] : 0;
        __syncthreads();
        s[t] += xv;
        __syncthreads();
    }
    int run = s[t] - tsum;
#pragma unroll
    for (int i = 0; i < 4; ++i) { int g = base + i; if (g < NN) offs[g] = run; run += v[i]; }
    if (t == 255) bsum[b] = s[255];
}

__global__ __launch_bounds__(128) void k_scan2(int* __restrict__ bsum, int nb)
{
    __shared__ int s[128];
    int t = threadIdx.x;
    int v = (t < nb) ? bsum[t] : 0;
    s[t] = v;
    __syncthreads();
    for (int d = 1; d < 128; d <<= 1) {
        int xv = (t >= d) ? s[t - d] : 0;
        __syncthreads();
        s[t] += xv;
        __syncthreads();
    }
    if (t < nb) bsum[t] = s[t] - v;
}

__global__ __launch_bounds__(256) void k_scan3(
    int* __restrict__ offs, const int* __restrict__ bsum, int* __restrict__ cursor)
{
    int g = blockIdx.x * 256 + threadIdx.x;
    if (g >= NN) return;
    int o = offs[g] + bsum[g >> 10];
    offs[g] = o;
    cursor[g] = o;
}

// ------------------------------------------------- range-partitioned fill
// 8 block-groups; group g emits only entries targeting nodes in its 1/8
// range, so each group's eplist write window (~1.6MB) stays cache-resident
// and lines collect all entries before writeback (was 101MB WRITE_SIZE flat,
// 8x amplification). Edges re-scanned 8x (cheap L2/L3 reads).
#define FILL_GROUPS 8
#define FILL_SUBBLK 256
#define RANGE_W (NN / FILL_GROUPS)   // 12500
__global__ __launch_bounds__(256) void k_fill(
    const int* __restrict__ fi, const int* __restrict__ ti,
    int* __restrict__ cursor, int2* __restrict__ eplist)
{
    int grp = blockIdx.x & (FILL_GROUPS - 1);
    int sub = blockIdx.x >> 3;
    int lo = grp * RANGE_W;
    int hi = lo + RANGE_W;
    for (int e = sub * 256 + threadIdx.x; e < NE; e += FILL_SUBBLK * 256) {
        int f = fi[e], t = ti[e];
        if (t >= lo && t < hi) {
            int p = atomicAdd(&cursor[t], 1);
            eplist[p] = make_int2(e, f);    // dir0: [h_f, h_t, e] -> t
        }
        if (f >= lo && f < hi) {
            int p = atomicAdd(&cursor[f], 1);
            eplist[p] = make_int2(e, t);    // dir1: [h_t, h_f, e] -> f
        }
    }
}

// ------------------------------------------------- gather: one wave per node
__global__ __launch_bounds__(256) void k_gather(
    const int* __restrict__ offs, const int* __restrict__ deg,
    const int2* __restrict__ eplist,
    const float* __restrict__ A, const float* __restrict__ B,
    const float* __restrict__ ef,
    const float* __restrict__ Wef, const float* __restrict__ bef,
    float* __restrict__ aggH)
{
    int wave = (blockIdx.x * 256 + threadIdx.x) >> 6;
    if (wave >= NN) return;
    int lane = threadIdx.x & 63;
    int half = lane >> 5;
    int c = lane & 31;
    float w[8];
#pragma unroll
    for (int j = 0; j < 8; ++j) w[j] = Wef[j * 32 + c];
    float kbase = B[(size_t)wave * 32 + c] + bef[c];
    int beg = offs[wave];
    int end = beg + deg[wave];
    float acc0 = 0.f, acc1 = 0.f;
    int i = beg + half;
    for (; i + 2 < end; i += 4) {
        int2 ep0 = eplist[i];
        int2 ep1 = eplist[i + 2];
        float a0 = A[(size_t)ep0.y * 32 + c];
        float a1 = A[(size_t)ep1.y * 32 + c];
        const float4* pf0 = (const float4*)(ef + (size_t)ep0.x * 8);
        const float4* pf1 = (const float4*)(ef + (size_t)ep1.x * 8);
        float4 e00 = pf0[0], e01 = pf0[1];
        float4 e10 = pf1[0], e11 = pf1[1];
        float s0 = kbase + a0;
        s0 = fmaf(e00.x, w[0], s0); s0 = fmaf(e00.y, w[1], s0);
        s0 = fmaf(e00.z, w[2], s0); s0 = fmaf(e00.w, w[3], s0);
        s0 = fmaf(e01.x, w[4], s0); s0 = fmaf(e01.y, w[5], s0);
        s0 = fmaf(e01.z, w[6], s0); s0 = fmaf(e01.w, w[7], s0);
        float s1 = kbase + a1;
        s1 = fmaf(e10.x, w[0], s1); s1 = fmaf(e10.y, w[1], s1);
        s1 = fmaf(e10.z, w[2], s1); s1 = fmaf(e10.w, w[3], s1);
        s1 = fmaf(e11.x, w[4], s1); s1 = fmaf(e11.y, w[5], s1);
        s1 = fmaf(e11.z, w[6], s1); s1 = fmaf(e11.w, w[7], s1);
        acc0 += fmaxf(s0, 0.f);
        acc1 += fmaxf(s1, 0.f);
    }
    for (; i < end; i += 2) {
        int2 ep = eplist[i];
        float a = A[(size_t)ep.y * 32 + c];
        const float4* pf = (const float4*)(ef + (size_t)ep.x * 8);
        float4 f0 = pf[0], f1 = pf[1];
        float s = kbase + a;
        s = fmaf(f0.x, w[0], s); s = fmaf(f0.y, w[1], s);
        s = fmaf(f0.z, w[2], s); s = fmaf(f0.w, w[3], s);
        s = fmaf(f1.x, w[4], s); s = fmaf(f1.y, w[5], s);
        s = fmaf(f1.z, w[6], s); s = fmaf(f1.w, w[7], s);
        acc0 += fmaxf(s, 0.f);
    }
    float acc = acc0 + acc1;
    acc += __shfl_down(acc, 32);
    if (lane < 32) aggH[(size_t)wave * 32 + c] = acc;
}

// ----------------------------------------- update v2: 2 threads per node
// Split by hidden-half with p = threadIdx.x>>7 so p is WAVE-UNIFORM: all
// weight addresses stay wave-uniform (broadcast loads; no per-lane weight
// streams). Halves exchange partial out[32] via +1-padded LDS (bank =
// (t+k)%32, conflict-free). p=0 writes h and A; p=1 writes B.
// Was: 1 thread/node, 1564 waves, VALUBusy 19%, 118us (latency-bound).
#define UPD_NPB 128
#define UPD_GRID ((NN + UPD_NPB - 1) / UPD_NPB)
__global__ __launch_bounds__(256) void k_update(
    const float* __restrict__ aggH, const int* __restrict__ deg,
    float* __restrict__ h,
    const float* __restrict__ mw2, const float* __restrict__ mb2,
    const float* __restrict__ uw1, const float* __restrict__ ub1,
    const float* __restrict__ uw2, const float* __restrict__ ub2,
    const float* __restrict__ mw1,
    float* __restrict__ A, float* __restrict__ B, int last)
{
    __shared__ float xch[256][33];
    int tl  = threadIdx.x & 127;     // node within block
    int p   = threadIdx.x >> 7;      // hidden-half; uniform across each wave
    int nid = blockIdx.x * UPD_NPB + tl;
    bool valid = nid < NN;
    int n = valid ? nid : (NN - 1);  // clamp: keep threads alive for barrier

    // load aggH[n], h[n]
    float av[32], hv[32];
    {
        const float4* pa  = (const float4*)(aggH + (size_t)n * 32);
        const float4* phv = (const float4*)(h + (size_t)n * 32);
#pragma unroll
        for (int i = 0; i < 8; ++i) {
            float4 v = pa[i];
            av[4*i] = v.x; av[4*i+1] = v.y; av[4*i+2] = v.z; av[4*i+3] = v.w;
            float4 u = phv[i];
            hv[4*i] = u.x; hv[4*i+1] = u.y; hv[4*i+2] = u.z; hv[4*i+3] = u.w;
        }
    }
    float dg = (float)deg[n];
    // agg = aggH @ mw2 + dg*mb2  (full 32-vec, duplicated in both halves)
    float agg[32];
#pragma unroll
    for (int k = 0; k < 32; ++k) agg[k] = dg * mb2[k];
#pragma unroll
    for (int i = 0; i < 32; ++i) {
        float r = av[i];
        const float4* wr = (const float4*)(mw2 + (size_t)i * 32);
#pragma unroll
        for (int k4 = 0; k4 < 8; ++k4) {
            float4 wv = wr[k4];
            agg[4*k4]   = fmaf(r, wv.x, agg[4*k4]);
            agg[4*k4+1] = fmaf(r, wv.y, agg[4*k4+1]);
            agg[4*k4+2] = fmaf(r, wv.z, agg[4*k4+2]);
            agg[4*k4+3] = fmaf(r, wv.w, agg[4*k4+3]);
        }
    }
    // hid half: global j = p*32 + jl
    float hid[32];
#pragma unroll
    for (int j = 0; j < 32; ++j) hid[j] = ub1[p * 32 + j];
#pragma unroll
    for (int i = 0; i < 32; ++i) {
        float r = agg[i];
        const float4* wr = (const float4*)(uw1 + (size_t)i * 64 + p * 32);
#pragma unroll
        for (int j4 = 0; j4 < 8; ++j4) {
            float4 wv = wr[j4];
            hid[4*j4]   = fmaf(r, wv.x, hid[4*j4]);
            hid[4*j4+1] = fmaf(r, wv.y, hid[4*j4+1]);
            hid[4*j4+2] = fmaf(r, wv.z, hid[4*j4+2]);
            hid[4*j4+3] = fmaf(r, wv.w, hid[4*j4+3]);
        }
    }
#pragma unroll
    for (int i = 0; i < 32; ++i) {
        float r = hv[i];
        const float4* wr = (const float4*)(uw1 + (size_t)(32 + i) * 64 + p * 32);
#pragma unroll
        for (int j4 = 0; j4 < 8; ++j4) {
            float4 wv = wr[j4];
            hid[4*j4]   = fmaf(r, wv.x, hid[4*j4]);
            hid[4*j4+1] = fmaf(r, wv.y, hid[4*j4+1]);
            hid[4*j4+2] = fmaf(r, wv.z, hid[4*j4+2]);
            hid[4*j4+3] = fmaf(r, wv.w, hid[4*j4+3]);
        }
    }
    // out partial over this half's hidden units
    float outp[32];
#pragma unroll
    for (int k = 0; k < 32; ++k) outp[k] = 0.f;
#pragma unroll
    for (int j = 0; j < 32; ++j) {
        float r = fmaxf(hid[j], 0.f);
        const float4* wr = (const float4*)(uw2 + (size_t)(p * 32 + j) * 32);
#pragma unroll
        for (int k4 = 0; k4 < 8; ++k4) {
            float4 wv = wr[k4];
            outp[4*k4]   = fmaf(r, wv.x, outp[4*k4]);
            outp[4*k4+1] = fmaf(r, wv.y, outp[4*k4+1]);
            outp[4*k4+2] = fmaf(r, wv.z, outp[4*k4+2]);
            outp[4*k4+3] = fmaf(r, wv.w, outp[4*k4+3]);
        }
    }
    // exchange partials across halves
#pragma unroll
    for (int k = 0; k < 32; ++k) xch[threadIdx.x][k] = outp[k];
    __syncthreads();
    const float* part = xch[threadIdx.x ^ 128];
    float hnew[32];
#pragma unroll
    for (int k = 0; k < 32; ++k)
        hnew[k] = hv[k] + outp[k] + part[k] + ub2[k];

    if (valid) {
        if (p == 0) {
            float4* ph = (float4*)(h + (size_t)n * 32);
#pragma unroll
            for (int i = 0; i < 8; ++i)
                ph[i] = make_float4(hnew[4*i], hnew[4*i+1], hnew[4*i+2], hnew[4*i+3]);
        }
        if (!last) {
            // p=0 -> A = hnew@mw1[0:32]; p=1 -> B = hnew@mw1[32:64]
            float acc[32];
#pragma unroll
            for (int c = 0; c < 32; ++c) acc[c] = 0.f;
            const float* wbase = mw1 + (size_t)(p * 32) * 32;
#pragma unroll
            for (int i = 0; i < 32; ++i) {
                float r = hnew[i];
                const float4* wr = (const float4*)(wbase + (size_t)i * 32);
#pragma unroll
                for (int c4 = 0; c4 < 8; ++c4) {
                    float4 wv = wr[c4];
                    acc[4*c4]   = fmaf(r, wv.x, acc[4*c4]);
                    acc[4*c4+1] = fmaf(r, wv.y, acc[4*c4+1]);
                    acc[4*c4+2] = fmaf(r, wv.z, acc[4*c4+2]);
                    acc[4*c4+3] = fmaf(r, wv.w, acc[4*c4+3]);
                }
            }
            float4* pd = (float4*)((p == 0 ? A : B) + (size_t)n * 32);
#pragma unroll
            for (int i = 0; i < 8; ++i)
                pd[i] = make_float4(acc[4*i], acc[4*i+1], acc[4*i+2], acc[4*i+3]);
        }
    }
}

// ------------------------------------------------ gated readout + graph sum
#define FN_WAVES 4096
#define FN_CHUNK ((NN + FN_WAVES - 1) / FN_WAVES)
__global__ __launch_bounds__(256) void k_final_nodes(
    const float* __restrict__ h, const int* __restrict__ gidx,
    const float* __restrict__ w1, const float* __restrict__ b1,
    float* __restrict__ gs)
{
    int wid = (blockIdx.x * 256 + threadIdx.x) >> 6;
    int lane = threadIdx.x & 63;
    int beg = wid * FN_CHUNK;
    if (beg >= NN) return;
    int end = beg + FN_CHUNK; if (end > NN) end = NN;

    const float bl = b1[lane];
    const float bh = b1[64 + lane];
    float acc = 0.f;
    int curq = -1;
    for (int n = beg; n < end; ++n) {
        int q = gidx[n];
        if (q != curq) {
            if (curq >= 0 && acc != 0.f)
                atomicAdd(&gs[(size_t)curq * 64 + lane], acc);
            acc = 0.f;
            curq = q;
        }
        float xv = h[(size_t)n * 32 + (lane & 31)];
        float gl = bl, gh = bh;
#pragma unroll
        for (int i = 0; i < 32; ++i) {
            float xi = __shfl(xv, i);
            gl = fmaf(xi, w1[(size_t)i * 128 + lane],      gl);
            gh = fmaf(xi, w1[(size_t)i * 128 + 64 + lane], gh);
        }
        acc += gh / (1.0f + expf(-gl));
    }
    if (curq >= 0)
        atomicAdd(&gs[(size_t)curq * 64 + lane], acc);
}

// ------------------------------------------------------- pair hinge readout
__global__ __launch_bounds__(64) void k_pairs(
    const float* __restrict__ gs, const float* __restrict__ w2,
    const float* __restrict__ b2, float* __restrict__ out)
{
    int p = blockIdx.x;
    int k = threadIdx.x;
    const float* gx = gs + (size_t)(2*p) * 64;
    const float* gy = gs + (size_t)(2*p+1) * 64;
    float xk = b2[k], yk = b2[k];
    for (int i = 0; i < 64; ++i) {
        float w = w2[i*64 + k];
        xk = fmaf(gx[i], w, xk);
        yk = fmaf(gy[i], w, yk);
    }
    float d = fabsf(yk - xk);
#pragma unroll
    for (int s = 1; s < 64; s <<= 1) d += __shfl_xor(d, s);
    if (k == 0) out[p] = d;
}

// ---------------------------------------------------------------- launcher
extern "C" void kernel_launch(void* const* d_in, const int* in_sizes, int n_in,
                              void* d_out, int out_size, void* d_ws, size_t ws_size,
                              hipStream_t stream)
{
    const float* node_features = (const float*)d_in[0];
    const float* edge_features = (const float*)d_in[1];
    const int*   from_idx      = (const int*)d_in[2];
    const int*   to_idx        = (const int*)d_in[3];
    const int*   graph_idx     = (const int*)d_in[4];
    const float* enc_node_w = (const float*)d_in[5];
    const float* enc_node_b = (const float*)d_in[6];
    const float* enc_edge_w = (const float*)d_in[7];
    const float* enc_edge_b = (const float*)d_in[8];
    const float* msg_w1 = (const float*)d_in[9];
    const float* msg_b1 = (const float*)d_in[10];
    const float* msg_w2 = (const float*)d_in[11];
    const float* msg_b2 = (const float*)d_in[12];
    const float* upd_w1 = (const float*)d_in[13];
    const float* upd_b1 = (const float*)d_in[14];
    const float* upd_w2 = (const float*)d_in[15];
    const float* upd_b2 = (const float*)d_in[16];
    const float* agg_w1 = (const float*)d_in[17];
    const float* agg_b1 = (const float*)d_in[18];
    const float* agg_w2 = (const float*)d_in[19];
    const float* agg_b2 = (const float*)d_in[20];
    float* out = (float*)d_out;

    char* wsp = (char*)d_ws;
    auto alloc = [&](size_t bytes) {
        char* r = wsp;
        wsp += (bytes + 255) & ~(size_t)255;
        return r;
    };
    float* h     = (float*)alloc((size_t)NN * 32 * 4);
    float* A     = (float*)alloc((size_t)NN * 32 * 4);
    float* B     = (float*)alloc((size_t)NN * 32 * 4);
    float* aggH  = (float*)alloc((size_t)NN * 32 * 4);
    float* gs    = (float*)alloc((size_t)NG * 64 * 4);
    int*   deg   = (int*)alloc((size_t)NN * 4);
    int*   offs  = (int*)alloc((size_t)NN * 4);
    int*   cursor= (int*)alloc((size_t)NN * 4);
    int2*  eplist= (int2*)alloc(((size_t)NENT + 16) * 8);
    int*   bsum  = (int*)alloc(128 * 4);
    float* Wef   = (float*)alloc(8 * 32 * 4);
    float* bef   = (float*)alloc(32 * 4);

    hipMemsetAsync(deg, 0, (size_t)NN * 4, stream);

    k_prep<<<1, 64, 0, stream>>>(enc_edge_w, enc_edge_b, msg_w1, msg_b1, Wef, bef);
    k_enc_nodes<<<(NN + 255) / 256, 256, 0, stream>>>(node_features, enc_node_w,
                                                      enc_node_b, msg_w1, h, A, B);

    k_count<<<NE / 256, 256, 0, stream>>>(from_idx, to_idx, deg);
    k_scan1<<<NB, 256, 0, stream>>>(deg, offs, bsum);
    k_scan2<<<1, 128, 0, stream>>>(bsum, NB);
    k_scan3<<<(NN + 255) / 256, 256, 0, stream>>>(offs, bsum, cursor);
    k_fill<<<FILL_GROUPS * FILL_SUBBLK, 256, 0, stream>>>(from_idx, to_idx, cursor, eplist);

    for (int it = 0; it < 3; ++it) {
        k_gather<<<NN / 4, 256, 0, stream>>>(offs, deg, eplist, A, B,
                                             edge_features, Wef, bef, aggH);
        k_update<<<UPD_GRID, 256, 0, stream>>>(aggH, deg, h,
                                               msg_w2, msg_b2,
                                               upd_w1, upd_b1,
                                               upd_w2, upd_b2,
                                               msg_w1, A, B, it == 2);
    }

    hipMemsetAsync(gs, 0, (size_t)NG * 64 * 4, stream);
    k_final_nodes<<<FN_WAVES / 4, 256, 0, stream>>>(h, graph_idx, agg_w1, agg_b1, gs);
    k_pairs<<<NG / 2, 64, 0, stream>>>(gs, agg_w2, agg_b2, out);
}

// Round 11
// 839.770 us; speedup vs baseline: 1.1805x; 1.1805x over previous
//
#include <hip/hip_runtime.h>
#include <math.h>

#define NN 100000
#define NE 800000
#define NG 512
#define NENT (2*NE)
#define NB ((NN + 1023)/1024)

__device__ __forceinline__ float rlane(float v, int l) {
    return __int_as_float(__builtin_amdgcn_readlane(__float_as_int(v), l));
}

// ---------------------------------------------------------------- prep:
// Wef = enc_ew @ mw1[64:80]; bef = mb1 + enc_eb @ mw1[64:80]
// M1  = mw2 @ uw1[0:32]  (32x64); c1 = mb2 @ uw1[0:32]  (64)
__global__ __launch_bounds__(64) void k_prep(
    const float* __restrict__ ew, const float* __restrict__ eb,
    const float* __restrict__ mw1, const float* __restrict__ mb1,
    const float* __restrict__ mw2, const float* __restrict__ mb2,
    const float* __restrict__ uw1,
    float* __restrict__ Wef, float* __restrict__ bef,
    float* __restrict__ M1, float* __restrict__ c1)
{
    int j = threadIdx.x;          // 0..63
    float cacc = 0.f;
    for (int t = 0; t < 32; ++t) cacc = fmaf(mb2[t], uw1[t * 64 + j], cacc);
    c1[j] = cacc;
    for (int i = 0; i < 32; ++i) {
        float acc = 0.f;
        for (int t = 0; t < 32; ++t) acc = fmaf(mw2[i * 32 + t], uw1[t * 64 + j], acc);
        M1[i * 64 + j] = acc;
    }
    if (j < 32) {
        int c = j;
        float bacc = mb1[c];
        for (int t = 0; t < 16; ++t) bacc = fmaf(eb[t], mw1[(64 + t) * 32 + c], bacc);
        bef[c] = bacc;
        for (int jj = 0; jj < 8; ++jj) {
            float acc = 0.f;
            for (int t = 0; t < 16; ++t) acc = fmaf(ew[jj * 16 + t], mw1[(64 + t) * 32 + c], acc);
            Wef[jj * 32 + c] = acc;
        }
    }
}

// ---------------------------------------------------------------- encoder:
// h = nf @ wn + bn ; A = h @ mw1[0:32] ; B = h @ mw1[32:64]
__global__ __launch_bounds__(256) void k_enc_nodes(
    const float* __restrict__ nf, const float* __restrict__ w,
    const float* __restrict__ bb, const float* __restrict__ mw1,
    float* __restrict__ h, float* __restrict__ A, float* __restrict__ B)
{
    int n = blockIdx.x * 256 + threadIdx.x;
    if (n >= NN) return;
    const float4* px = (const float4*)(nf + (size_t)n * 16);
    float4 x[4];
#pragma unroll
    for (int i = 0; i < 4; ++i) x[i] = px[i];
    float out[32];
#pragma unroll
    for (int j = 0; j < 32; ++j) out[j] = bb[j];
#pragma unroll
    for (int i = 0; i < 4; ++i) {
#pragma unroll
        for (int j = 0; j < 32; ++j) {
            out[j] = fmaf(x[i].x, w[(4*i+0)*32 + j], out[j]);
            out[j] = fmaf(x[i].y, w[(4*i+1)*32 + j], out[j]);
            out[j] = fmaf(x[i].z, w[(4*i+2)*32 + j], out[j]);
            out[j] = fmaf(x[i].w, w[(4*i+3)*32 + j], out[j]);
        }
    }
    float4* po = (float4*)(h + (size_t)n * 32);
#pragma unroll
    for (int j = 0; j < 8; ++j)
        po[j] = make_float4(out[4*j], out[4*j+1], out[4*j+2], out[4*j+3]);

    float Av[32], Bv[32];
#pragma unroll
    for (int c = 0; c < 32; ++c) { Av[c] = 0.f; Bv[c] = 0.f; }
#pragma unroll
    for (int i = 0; i < 32; ++i) {
        float r = out[i];
        const float* wra = mw1 + (size_t)i * 32;
        const float* wrb = mw1 + (size_t)(32 + i) * 32;
#pragma unroll
        for (int c = 0; c < 32; ++c) {
            Av[c] = fmaf(r, wra[c], Av[c]);
            Bv[c] = fmaf(r, wrb[c], Bv[c]);
        }
    }
    float4* pA = (float4*)(A + (size_t)n * 32);
    float4* pB = (float4*)(B + (size_t)n * 32);
#pragma unroll
    for (int j = 0; j < 8; ++j) {
        pA[j] = make_float4(Av[4*j], Av[4*j+1], Av[4*j+2], Av[4*j+3]);
        pB[j] = make_float4(Bv[4*j], Bv[4*j+1], Bv[4*j+2], Bv[4*j+3]);
    }
}

// ---------------------------------------------------------------- CSR build
__global__ __launch_bounds__(256) void k_count(
    const int* __restrict__ fi, const int* __restrict__ ti, int* __restrict__ deg)
{
    int e = blockIdx.x * 256 + threadIdx.x;
    if (e >= NE) return;
    atomicAdd(&deg[ti[e]], 1);
    atomicAdd(&deg[fi[e]], 1);
}

__global__ __launch_bounds__(256) void k_scan1(
    const int* __restrict__ deg, int* __restrict__ offs, int* __restrict__ bsum)
{
    __shared__ int s[256];
    int b = blockIdx.x, t = threadIdx.x;
    int base = b * 1024 + t * 4;
    int v[4];
#pragma unroll
    for (int i = 0; i < 4; ++i) { int g = base + i; v[i] = (g < NN) ? deg[g] : 0; }
    int tsum = v[0] + v[1] + v[2] + v[3];
    s[t] = tsum;
    __syncthreads();
    for (int d = 1; d < 256; d <<= 1) {
        int xv = (t >= d) ? s[t - d] : 0;
        __syncthreads();
        s[t] += xv;
        __syncthreads();
    }
    int run = s[t] - tsum;
#pragma unroll
    for (int i = 0; i < 4; ++i) { int g = base + i; if (g < NN) offs[g] = run; run += v[i]; }
    if (t == 255) bsum[b] = s[255];
}

__global__ __launch_bounds__(128) void k_scan2(int* __restrict__ bsum, int nb)
{
    __shared__ int s[128];
    int t = threadIdx.x;
    int v = (t < nb) ? bsum[t] : 0;
    s[t] = v;
    __syncthreads();
    for (int d = 1; d < 128; d <<= 1) {
        int xv = (t >= d) ? s[t - d] : 0;
        __syncthreads();
        s[t] += xv;
        __syncthreads();
    }
    if (t < nb) bsum[t] = s[t] - v;
}

__global__ __launch_bounds__(256) void k_scan3(
    int* __restrict__ offs, const int* __restrict__ bsum, int* __restrict__ cursor)
{
    int g = blockIdx.x * 256 + threadIdx.x;
    if (g >= NN) return;
    int o = offs[g] + bsum[g >> 10];
    offs[g] = o;
    cursor[g] = o;
}

// ------------------------------------------------- range-partitioned fill
#define FILL_GROUPS 8
#define FILL_SUBBLK 256
#define RANGE_W (NN / FILL_GROUPS)   // 12500
__global__ __launch_bounds__(256) void k_fill(
    const int* __restrict__ fi, const int* __restrict__ ti,
    int* __restrict__ cursor, int2* __restrict__ eplist)
{
    int grp = blockIdx.x & (FILL_GROUPS - 1);
    int sub = blockIdx.x >> 3;
    int lo = grp * RANGE_W;
    int hi = lo + RANGE_W;
    for (int e = sub * 256 + threadIdx.x; e < NE; e += FILL_SUBBLK * 256) {
        int f = fi[e], t = ti[e];
        if (t >= lo && t < hi) {
            int p = atomicAdd(&cursor[t], 1);
            eplist[p] = make_int2(e, f);    // dir0: [h_f, h_t, e] -> t
        }
        if (f >= lo && f < hi) {
            int p = atomicAdd(&cursor[f], 1);
            eplist[p] = make_int2(e, t);    // dir1: [h_t, h_f, e] -> f
        }
    }
}

// ------------------------------------------------- gather: one wave per node
__global__ __launch_bounds__(256) void k_gather(
    const int* __restrict__ offs, const int* __restrict__ deg,
    const int2* __restrict__ eplist,
    const float* __restrict__ A, const float* __restrict__ B,
    const float* __restrict__ ef,
    const float* __restrict__ Wef, const float* __restrict__ bef,
    float* __restrict__ aggH)
{
    int wave = (blockIdx.x * 256 + threadIdx.x) >> 6;
    if (wave >= NN) return;
    int lane = threadIdx.x & 63;
    int half = lane >> 5;
    int c = lane & 31;
    float w[8];
#pragma unroll
    for (int j = 0; j < 8; ++j) w[j] = Wef[j * 32 + c];
    float kbase = B[(size_t)wave * 32 + c] + bef[c];
    int beg = offs[wave];
    int end = beg + deg[wave];
    float acc0 = 0.f, acc1 = 0.f;
    int i = beg + half;
    for (; i + 2 < end; i += 4) {
        int2 ep0 = eplist[i];
        int2 ep1 = eplist[i + 2];
        float a0 = A[(size_t)ep0.y * 32 + c];
        float a1 = A[(size_t)ep1.y * 32 + c];
        const float4* pf0 = (const float4*)(ef + (size_t)ep0.x * 8);
        const float4* pf1 = (const float4*)(ef + (size_t)ep1.x * 8);
        float4 e00 = pf0[0], e01 = pf0[1];
        float4 e10 = pf1[0], e11 = pf1[1];
        float s0 = kbase + a0;
        s0 = fmaf(e00.x, w[0], s0); s0 = fmaf(e00.y, w[1], s0);
        s0 = fmaf(e00.z, w[2], s0); s0 = fmaf(e00.w, w[3], s0);
        s0 = fmaf(e01.x, w[4], s0); s0 = fmaf(e01.y, w[5], s0);
        s0 = fmaf(e01.z, w[6], s0); s0 = fmaf(e01.w, w[7], s0);
        float s1 = kbase + a1;
        s1 = fmaf(e10.x, w[0], s1); s1 = fmaf(e10.y, w[1], s1);
        s1 = fmaf(e10.z, w[2], s1); s1 = fmaf(e10.w, w[3], s1);
        s1 = fmaf(e11.x, w[4], s1); s1 = fmaf(e11.y, w[5], s1);
        s1 = fmaf(e11.z, w[6], s1); s1 = fmaf(e11.w, w[7], s1);
        acc0 += fmaxf(s0, 0.f);
        acc1 += fmaxf(s1, 0.f);
    }
    for (; i < end; i += 2) {
        int2 ep = eplist[i];
        float a = A[(size_t)ep.y * 32 + c];
        const float4* pf = (const float4*)(ef + (size_t)ep.x * 8);
        float4 f0 = pf[0], f1 = pf[1];
        float s = kbase + a;
        s = fmaf(f0.x, w[0], s); s = fmaf(f0.y, w[1], s);
        s = fmaf(f0.z, w[2], s); s = fmaf(f0.w, w[3], s);
        s = fmaf(f1.x, w[4], s); s = fmaf(f1.y, w[5], s);
        s = fmaf(f1.z, w[6], s); s = fmaf(f1.w, w[7], s);
        acc0 += fmaxf(s, 0.f);
    }
    float acc = acc0 + acc1;
    acc += __shfl_down(acc, 32);
    if (lane < 32) aggH[(size_t)wave * 32 + c] = acc;
}

// ---------------------------------------- update v3: one wave per node-chunk
// Lane j holds WEIGHT COLUMNS in VGPRs (loaded once, reused over ~49 nodes):
// wM=M1[:,j], wU=uw1_bot[:,j], w2f=uw2[:,c], w1r=mw1[half-block][:,c].
// Inputs (aggH/h rows) are wave-uniform -> scalar-load path (wid is
// readfirstlane'd). Broadcasts via v_readlane (VALU; LDS pipe idle).
// hid_j = ub1[j] + dg*c1[j] + aggH.M1[:,j] + h.uw1b[:,j]   (agg phase folded)
// out_c = sum_j relu(hid_j)*uw2[j][c]; hnew = h + out + ub2; A/B = hnew@mw1.
// v1: 118us (1:1 weight-load:FMA, latency-bound); v2: 148us (LDS barrier).
#define U3_WAVES 2048
#define U3_CHUNK ((NN + U3_WAVES - 1) / U3_WAVES)   // 49
__global__ __launch_bounds__(256) void k_update(
    const float* __restrict__ aggH, const int* __restrict__ deg,
    float* __restrict__ h,
    const float* __restrict__ M1, const float* __restrict__ c1,
    const float* __restrict__ uw1, const float* __restrict__ ub1,
    const float* __restrict__ uw2, const float* __restrict__ ub2,
    const float* __restrict__ mw1,
    float* __restrict__ A, float* __restrict__ B, int last)
{
    int wid = __builtin_amdgcn_readfirstlane((int)((blockIdx.x * 256 + threadIdx.x) >> 6));
    int lane = threadIdx.x & 63;
    int c = lane & 31;
    int half = lane >> 5;
    int n0 = wid * U3_CHUNK;
    if (n0 >= NN) return;
    int n1 = n0 + U3_CHUNK; if (n1 > NN) n1 = NN;

    float wM[32], wU[32], w2f[64], w1r[32];
#pragma unroll
    for (int i = 0; i < 32; ++i) wM[i] = M1[i * 64 + lane];
#pragma unroll
    for (int i = 0; i < 32; ++i) wU[i] = uw1[(size_t)(32 + i) * 64 + lane];
#pragma unroll
    for (int j = 0; j < 64; ++j) w2f[j] = uw2[(size_t)j * 32 + c];
#pragma unroll
    for (int i = 0; i < 32; ++i) w1r[i] = mw1[(size_t)(half * 32 + i) * 32 + c];
    const float blane = ub1[lane];
    const float c1l = c1[lane];
    const float b2c = ub2[c];

    for (int n = n0; n < n1; ++n) {
        const float4* pa = (const float4*)(aggH + (size_t)n * 32);
        const float4* ph = (const float4*)(h + (size_t)n * 32);
        float dg = (float)deg[n];
        float hc = h[(size_t)n * 32 + c];          // per-lane channel value
        float h0 = fmaf(dg, c1l, blane), h1 = 0.f; // dual acc: break dep chain
#pragma unroll
        for (int q = 0; q < 8; ++q) {
            float4 va = pa[q];
            h0 = fmaf(va.x, wM[4*q+0], h0);
            h1 = fmaf(va.y, wM[4*q+1], h1);
            h0 = fmaf(va.z, wM[4*q+2], h0);
            h1 = fmaf(va.w, wM[4*q+3], h1);
        }
#pragma unroll
        for (int q = 0; q < 8; ++q) {
            float4 vh = ph[q];
            h0 = fmaf(vh.x, wU[4*q+0], h0);
            h1 = fmaf(vh.y, wU[4*q+1], h1);
            h0 = fmaf(vh.z, wU[4*q+2], h0);
            h1 = fmaf(vh.w, wU[4*q+3], h1);
        }
        float hr = fmaxf(h0 + h1, 0.f);
        float o0 = 0.f, o1 = 0.f;
#pragma unroll
        for (int j = 0; j < 64; j += 2) {
            o0 = fmaf(rlane(hr, j),     w2f[j],     o0);
            o1 = fmaf(rlane(hr, j + 1), w2f[j + 1], o1);
        }
        float hnew = hc + o0 + o1 + b2c;
        if (lane < 32) h[(size_t)n * 32 + lane] = hnew;
        if (!last) {
            float a0 = 0.f, a1 = 0.f;
#pragma unroll
            for (int i = 0; i < 32; i += 2) {
                a0 = fmaf(rlane(hnew, i),     w1r[i],     a0);
                a1 = fmaf(rlane(hnew, i + 1), w1r[i + 1], a1);
            }
            float* dst = (half == 0) ? A : B;
            dst[(size_t)n * 32 + c] = a0 + a1;
        }
    }
}

// ------------------------------------------------ gated readout + graph sum
#define FN_WAVES 4096
#define FN_CHUNK ((NN + FN_WAVES - 1) / FN_WAVES)
__global__ __launch_bounds__(256) void k_final_nodes(
    const float* __restrict__ h, const int* __restrict__ gidx,
    const float* __restrict__ w1, const float* __restrict__ b1,
    float* __restrict__ gs)
{
    int wid = (blockIdx.x * 256 + threadIdx.x) >> 6;
    int lane = threadIdx.x & 63;
    int beg = wid * FN_CHUNK;
    if (beg >= NN) return;
    int end = beg + FN_CHUNK; if (end > NN) end = NN;

    const float bl = b1[lane];
    const float bh = b1[64 + lane];
    float acc = 0.f;
    int curq = -1;
    for (int n = beg; n < end; ++n) {
        int q = gidx[n];
        if (q != curq) {
            if (curq >= 0 && acc != 0.f)
                atomicAdd(&gs[(size_t)curq * 64 + lane], acc);
            acc = 0.f;
            curq = q;
        }
        float xv = h[(size_t)n * 32 + (lane & 31)];
        float gl = bl, gh = bh;
#pragma unroll
        for (int i = 0; i < 32; ++i) {
            float xi = __shfl(xv, i);
            gl = fmaf(xi, w1[(size_t)i * 128 + lane],      gl);
            gh = fmaf(xi, w1[(size_t)i * 128 + 64 + lane], gh);
        }
        acc += gh / (1.0f + expf(-gl));
    }
    if (curq >= 0)
        atomicAdd(&gs[(size_t)curq * 64 + lane], acc);
}

// ------------------------------------------------------- pair hinge readout
__global__ __launch_bounds__(64) void k_pairs(
    const float* __restrict__ gs, const float* __restrict__ w2,
    const float* __restrict__ b2, float* __restrict__ out)
{
    int p = blockIdx.x;
    int k = threadIdx.x;
    const float* gx = gs + (size_t)(2*p) * 64;
    const float* gy = gs + (size_t)(2*p+1) * 64;
    float xk = b2[k], yk = b2[k];
    for (int i = 0; i < 64; ++i) {
        float w = w2[i*64 + k];
        xk = fmaf(gx[i], w, xk);
        yk = fmaf(gy[i], w, yk);
    }
    float d = fabsf(yk - xk);
#pragma unroll
    for (int s = 1; s < 64; s <<= 1) d += __shfl_xor(d, s);
    if (k == 0) out[p] = d;
}

// ---------------------------------------------------------------- launcher
extern "C" void kernel_launch(void* const* d_in, const int* in_sizes, int n_in,
                              void* d_out, int out_size, void* d_ws, size_t ws_size,
                              hipStream_t stream)
{
    const float* node_features = (const float*)d_in[0];
    const float* edge_features = (const float*)d_in[1];
    const int*   from_idx      = (const int*)d_in[2];
    const int*   to_idx        = (const int*)d_in[3];
    const int*   graph_idx     = (const int*)d_in[4];
    const float* enc_node_w = (const float*)d_in[5];
    const float* enc_node_b = (const float*)d_in[6];
    const float* enc_edge_w = (const float*)d_in[7];
    const float* enc_edge_b = (const float*)d_in[8];
    const float* msg_w1 = (const float*)d_in[9];
    const float* msg_b1 = (const float*)d_in[10];
    const float* msg_w2 = (const float*)d_in[11];
    const float* msg_b2 = (const float*)d_in[12];
    const float* upd_w1 = (const float*)d_in[13];
    const float* upd_b1 = (const float*)d_in[14];
    const float* upd_w2 = (const float*)d_in[15];
    const float* upd_b2 = (const float*)d_in[16];
    const float* agg_w1 = (const float*)d_in[17];
    const float* agg_b1 = (const float*)d_in[18];
    const float* agg_w2 = (const float*)d_in[19];
    const float* agg_b2 = (const float*)d_in[20];
    float* out = (float*)d_out;

    char* wsp = (char*)d_ws;
    auto alloc = [&](size_t bytes) {
        char* r = wsp;
        wsp += (bytes + 255) & ~(size_t)255;
        return r;
    };
    float* h     = (float*)alloc((size_t)NN * 32 * 4);
    float* A     = (float*)alloc((size_t)NN * 32 * 4);
    float* B     = (float*)alloc((size_t)NN * 32 * 4);
    float* aggH  = (float*)alloc((size_t)NN * 32 * 4);
    float* gs    = (float*)alloc((size_t)NG * 64 * 4);
    int*   deg   = (int*)alloc((size_t)NN * 4);
    int*   offs  = (int*)alloc((size_t)NN * 4);
    int*   cursor= (int*)alloc((size_t)NN * 4);
    int2*  eplist= (int2*)alloc(((size_t)NENT + 16) * 8);
    int*   bsum  = (int*)alloc(128 * 4);
    float* Wef   = (float*)alloc(8 * 32 * 4);
    float* bef   = (float*)alloc(32 * 4);
    float* M1    = (float*)alloc(32 * 64 * 4);
    float* c1    = (float*)alloc(64 * 4);

    hipMemsetAsync(deg, 0, (size_t)NN * 4, stream);

    k_prep<<<1, 64, 0, stream>>>(enc_edge_w, enc_edge_b, msg_w1, msg_b1,
                                 msg_w2, msg_b2, upd_w1, Wef, bef, M1, c1);
    k_enc_nodes<<<(NN + 255) / 256, 256, 0, stream>>>(node_features, enc_node_w,
                                                      enc_node_b, msg_w1, h, A, B);

    k_count<<<NE / 256, 256, 0, stream>>>(from_idx, to_idx, deg);
    k_scan1<<<NB, 256, 0, stream>>>(deg, offs, bsum);
    k_scan2<<<1, 128, 0, stream>>>(bsum, NB);
    k_scan3<<<(NN + 255) / 256, 256, 0, stream>>>(offs, bsum, cursor);
    k_fill<<<FILL_GROUPS * FILL_SUBBLK, 256, 0, stream>>>(from_idx, to_idx, cursor, eplist);

    for (int it = 0; it < 3; ++it) {
        k_gather<<<NN / 4, 256, 0, stream>>>(offs, deg, eplist, A, B,
                                             edge_features, Wef, bef, aggH);
        k_update<<<U3_WAVES / 4, 256, 0, stream>>>(aggH, deg, h,
                                                   M1, c1,
                                                   upd_w1, upd_b1,
                                                   upd_w2, upd_b2,
                                                   msg_w1, A, B, it == 2);
    }

    hipMemsetAsync(gs, 0, (size_t)NG * 64 * 4, stream);
    k_final_nodes<<<FN_WAVES / 4, 256, 0, stream>>>(h, graph_idx, agg_w1, agg_b1, gs);
    k_pairs<<<NG / 2, 64, 0, stream>>>(gs, agg_w2, agg_b2, out);
}